// Round 9
// baseline (184.391 us; speedup 1.0000x reference)
//
#include <hip/hip_runtime.h>
#include <math.h>

#define NROWS 131072
#define DIM   64
#define KCENT 1024
#define DECAY 0.99f
#define EPS_  1e-5f
#define INV_ND (1.0f / ((float)NROWS * (float)DIM))

typedef unsigned int u32;
typedef unsigned short u16;
typedef __attribute__((ext_vector_type(8))) short short8b;
typedef __attribute__((ext_vector_type(16))) float floatx16;

// ---------------- ws layout (float elements) ----------------
// csum    [K*D]    @ 0        (zeroed by k_ctrans)
// cnt     [K]      @ 65536    (int, zeroed by k_ctrans)
// cs      [K]      @ 66560    (written by k_scatter block 0)
// (cnewT slot)     @ 67584    (UNUSED in v10 — centroid rows computed on the fly)
// ind     [N]      @ 133120   (int)
// pk      [N]      @ 264192   (int2: {row, cluster} in sorted order)
// xsqp    [512]    @ 526336   (float; per-block sum(x^2) partials)
// cursor16[K*16]   @ 527360   (int, 64B-spread atomic cursors; zeroed by k_ctrans)
// centB   [K*68]   @ 543744   (u32: bf16 hi 32dw | lo 32dw | csq@64 | pad; 272B rows)
//
// loss: mean((x-q)^2) = [Sum x^2 - 2 Sum<v_k,csum_k> + Sum cnt_k*||v_k||^2]/(N*D)
// v10 vs v9 (178us): k_newcent + k_out replaced by pk-driven k_finish — per
// cluster-run compute centroid row v[d] on the fly (lane=dim), store to all
// rows of the run, add the per-cluster loss term once at the run's global
// start. cnewT never materialized; ind not re-read. Nontemporal x loads
// (segsum) and out stores (finish) keep the 2x33.5MB streams from evicting
// the hot csum/cs/avg lines in L2. Launches 6 -> 5.

__device__ inline u16 bf16rne(float f) {
    u32 u = __float_as_uint(f);
    return (u16)((u + 0x7FFFu + ((u >> 16) & 1u)) >> 16);
}

// ---------- K1: centroid transpose/split + zero csum/cnt/cursor16 ----------
__global__ void k_ctrans(const float* __restrict__ cent, u32* __restrict__ centB,
                         float* __restrict__ zero_base, int* __restrict__ cursor16) {
    const int t = threadIdx.x, b = blockIdx.x;
    const int gid = b * 256 + t;                 // 0..8191
    float4 z = make_float4(0.f, 0.f, 0.f, 0.f);
    for (int i = gid; i < 16640; i += 8192) ((float4*)zero_base)[i] = z;   // csum+cnt
    if (gid < 4096) ((int4*)cursor16)[gid] = make_int4(0, 0, 0, 0);

    const int k   = b * 32 + (t & 31);
    const int grp = t >> 5;                      // 0..7
    u32* row = centB + (size_t)k * 68;
    float csq = 0.f;
#pragma unroll
    for (int j = 0; j < 4; ++j) {
        int w = grp * 4 + j;                     // dim-pair: dims 2w, 2w+1
        float f0 = cent[(2 * w) * KCENT + k];
        float f1 = cent[(2 * w + 1) * KCENT + k];
        u16 h0 = bf16rne(f0), h1 = bf16rne(f1);
        u16 s0 = bf16rne(f0 - __uint_as_float((u32)h0 << 16));
        u16 s1 = bf16rne(f1 - __uint_as_float((u32)h1 << 16));
        csq = fmaf(f0, f0, fmaf(f1, f1, csq));
        row[w]      = (u32)h0 | ((u32)h1 << 16);
        row[32 + w] = (u32)s0 | ((u32)s1 << 16);
    }
    __shared__ float csq_p[256];
    csq_p[t] = csq;
    __syncthreads();
    if (t < 32) {
        float s = 0.f;
#pragma unroll
        for (int g = 0; g < 8; ++g) s += csq_p[g * 32 + t];
        centB[(size_t)(b * 32 + t) * 68 + 64] = __float_as_uint(s);
    }
}

// ---------- K2: MFMA assignment (R1 structure, best measured) ----------
__global__ __launch_bounds__(512, 4) void k_assign(
    const float* __restrict__ x, const u32* __restrict__ centB,
    int* __restrict__ ind, int* __restrict__ cnt, float* __restrict__ xsqp) {
    __shared__ __align__(16) char buf[2][17408];
    __shared__ int hist[KCENT];
    __shared__ float xsq_lds;
    const int tid  = threadIdx.x;
    const int lane = tid & 63;
    const int wid  = tid >> 6;
    const int half = lane >> 5;
    const int nl   = lane & 31;

    hist[tid] = 0;
    hist[tid + 512] = 0;
    if (tid == 0) xsq_lds = 0.f;

    const int rowbase = blockIdx.x * 256 + wid * 32;

    short8b ah[4], al[4];
    float xsq = 0.f;
    {
        const float* xr = x + (size_t)(rowbase + nl) * DIM;
#pragma unroll
        for (int t4 = 0; t4 < 4; ++t4) {
            int d0 = t4 * 16 + half * 8;
            float4 f0 = *(const float4*)(xr + d0);
            float4 f1 = *(const float4*)(xr + d0 + 4);
            float fv[8] = {f0.x, f0.y, f0.z, f0.w, f1.x, f1.y, f1.z, f1.w};
            short8b va, vb;
#pragma unroll
            for (int j = 0; j < 8; ++j) {
                xsq = fmaf(fv[j], fv[j], xsq);
                u16 h = bf16rne(fv[j]);
                float lo = fv[j] - __uint_as_float((u32)h << 16);
                va[j] = (short)h;
                vb[j] = (short)bf16rne(lo);
            }
            ah[t4] = va;
            al[t4] = vb;
        }
    }
#pragma unroll
    for (int m = 1; m < 64; m <<= 1) xsq += __shfl_xor(xsq, m, 64);

    float best[16];
#pragma unroll
    for (int r = 0; r < 16; ++r) best[r] = __uint_as_float(0xFF800000u);

    const char* gbase = (const char*)centB;
#define STAGE(KT, DST)                                                              \
    {                                                                               \
        const char* _src = gbase + (size_t)(KT) * 17408;                            \
        for (int b = wid; b < 17; b += 8) {                                         \
            __builtin_amdgcn_global_load_lds(                                       \
                (const __attribute__((address_space(1))) u32*)(_src + b * 1024 +    \
                                                               lane * 16),          \
                (__attribute__((address_space(3))) u32*)((DST) + b * 1024),         \
                16, 0, 0);                                                          \
        }                                                                           \
    }

    STAGE(0, buf[0]);
    __syncthreads();
    if (lane == 0) atomicAdd(&xsq_lds, xsq);

    for (int kt = 0; kt < 16; ++kt) {
        char* b = buf[kt & 1];
        if (kt < 15) STAGE(kt + 1, buf[(kt + 1) & 1]);

#pragma unroll
        for (int sub = 0; sub < 2; ++sub) {
            const char* base = b + (size_t)(sub * 32 + nl) * 272 + half * 16;
            short8b bh[4], bl[4];
#pragma unroll
            for (int t4 = 0; t4 < 4; ++t4) bh[t4] = *(const short8b*)(base + t4 * 32);
#pragma unroll
            for (int t4 = 0; t4 < 4; ++t4) bl[t4] = *(const short8b*)(base + 128 + t4 * 32);
            float cq = *(const float*)(b + (size_t)(sub * 32 + nl) * 272 + 256);
            float mh = -0.5f * cq;

            floatx16 acc;
#pragma unroll
            for (int i = 0; i < 16; ++i) acc[i] = mh;
#pragma unroll
            for (int t4 = 0; t4 < 4; ++t4)
                acc = __builtin_amdgcn_mfma_f32_32x32x16_bf16(ah[t4], bh[t4], acc, 0, 0, 0);
#pragma unroll
            for (int t4 = 0; t4 < 4; ++t4)
                acc = __builtin_amdgcn_mfma_f32_32x32x16_bf16(ah[t4], bl[t4], acc, 0, 0, 0);
#pragma unroll
            for (int t4 = 0; t4 < 4; ++t4)
                acc = __builtin_amdgcn_mfma_f32_32x32x16_bf16(al[t4], bh[t4], acc, 0, 0, 0);

            const u32 tag = (u32)(kt * 2 + sub);
#pragma unroll
            for (int r = 0; r < 16; ++r) {
                u32 pkv = (__float_as_uint(acc[r]) & 0xFFFFFFE0u) | tag;
                best[r] = fmaxf(best[r], __uint_as_float(pkv));
            }
        }
        __syncthreads();
    }
#undef STAGE

#pragma unroll
    for (int r = 0; r < 16; ++r) {
        float b0 = best[r];
        int   i0 = ((int)(__float_as_uint(b0) & 31u) << 5) | nl;
#pragma unroll
        for (int m = 1; m < 32; m <<= 1) {
            float bp = __shfl_xor(b0, m, 64);
            int   ip = __shfl_xor(i0, m, 64);
            if (bp > b0 || (bp == b0 && ip < i0)) { b0 = bp; i0 = ip; }
        }
        if (nl == 0) {
            int mrow = (r & 3) + 8 * (r >> 2) + 4 * half;
            ind[rowbase + mrow] = i0;
            atomicAdd(&hist[i0], 1);
        }
    }
    __syncthreads();
    {
        int v0 = hist[tid];
        if (v0) atomicAdd(&cnt[tid], v0);
        int v1 = hist[tid + 512];
        if (v1) atomicAdd(&cnt[tid + 512], v1);
    }
    if (tid == 0) xsqp[blockIdx.x] = xsq_lds;
}

// ---------- K3: scatter + fused per-block redundant scan ----------
__global__ __launch_bounds__(256) void k_scatter(
    const float* __restrict__ cluster_size, const int* __restrict__ cnt,
    const int* __restrict__ ind, const float* __restrict__ xsqp,
    int* __restrict__ cursor16, int2* __restrict__ pk,
    float* __restrict__ cs, float* __restrict__ loss) {
    __shared__ int   lh[KCENT];
    __shared__ int   start_l[KCENT];
    __shared__ int   wtot[4];
    __shared__ float wsum[4];
    __shared__ float red4[4];
    const int t = threadIdx.x, b = blockIdx.x;
    const int lane = t & 63, w = t >> 6;

    // Phase A: scan inputs + wave-level partials + lh zero
    const int4   cv = ((const int4*)cnt)[t];             // k = 4t..4t+3
    const float4 cz = ((const float4*)cluster_size)[t];
    float cls0 = DECAY * cz.x + (1.0f - DECAY) * (float)cv.x;
    float cls1 = DECAY * cz.y + (1.0f - DECAY) * (float)cv.y;
    float cls2 = DECAY * cz.z + (1.0f - DECAY) * (float)cv.z;
    float cls3 = DECAY * cz.w + (1.0f - DECAY) * (float)cv.w;

    int s1 = cv.x, s2 = s1 + cv.y, s3 = s2 + cv.z, s4 = s3 + cv.w;
    int inc = s4;
#pragma unroll
    for (int m = 1; m < 64; m <<= 1) {
        int u = __shfl_up(inc, m, 64);
        if (lane >= m) inc += u;
    }
    float fsum = cls0 + cls1 + cls2 + cls3;
#pragma unroll
    for (int m = 1; m < 64; m <<= 1) fsum += __shfl_xor(fsum, m, 64);
    if (lane == 63) wtot[w] = inc;
    if (lane == 0)  wsum[w] = fsum;
    lh[4 * t + 0] = 0; lh[4 * t + 1] = 0; lh[4 * t + 2] = 0; lh[4 * t + 3] = 0;
    if (b == 0 && t < 128) {
        float v = xsqp[t] + xsqp[t + 128] + xsqp[t + 256] + xsqp[t + 384];
#pragma unroll
        for (int m = 1; m < 64; m <<= 1) v += __shfl_xor(v, m, 64);
        if (lane == 0) red4[w] = v;
    }
    __syncthreads();

    // Phase B: start_l; block 0 emits cs + loss x^2 term; ranks via LDS atomics
    int woffv = 0;
#pragma unroll
    for (int i = 0; i < 4; ++i) if (i < w) woffv += wtot[i];
    const int base0 = woffv + inc - s4;
    start_l[4 * t + 0] = base0;
    start_l[4 * t + 1] = base0 + s1;
    start_l[4 * t + 2] = base0 + s2;
    start_l[4 * t + 3] = base0 + s3;
    if (b == 0) {
        const float ntot = wsum[0] + wsum[1] + wsum[2] + wsum[3];
        const float csc = ntot / (ntot + KCENT * EPS_);
        ((float4*)cs)[t] = make_float4((cls0 + EPS_) * csc, (cls1 + EPS_) * csc,
                                       (cls2 + EPS_) * csc, (cls3 + EPS_) * csc);
        if (t == 0) loss[0] = (red4[0] + red4[1]) * INV_ND;
    }
    const int n  = b * 256 + t;
    const int bi = ind[n];
    const int rank = atomicAdd(&lh[bi], 1);
    __syncthreads();

    // Phase C: one global cursor claim per distinct cluster in block
#pragma unroll
    for (int i = 0; i < 4; ++i) {
        int k = t + i * 256;
        int c = lh[k];
        int bse = 0;
        if (c) bse = atomicAdd(&cursor16[k * 16], c);
        lh[k] = start_l[k] + bse;
    }
    __syncthreads();

    pk[lh[bi] + rank] = make_int2(n, bi);
}

// ---------- K4: segment sum, 4-row ILP, nontemporal x (read-once stream) ----------
__global__ __launch_bounds__(256) void k_segsum(
    const float* __restrict__ x, const int2* __restrict__ pk,
    float* __restrict__ csum) {
    const int wgid = blockIdx.x * 4 + (threadIdx.x >> 6);  // 0..4095
    const int lane = threadIdx.x & 63;
    const int r0   = wgid * 32;

    float acc = 0.f;
    int cur = pk[r0].y;
    for (int r = r0; r < r0 + 32; r += 4) {
        int2 a = pk[r];                   // wave-uniform scalar loads
        int2 b = pk[r + 1];
        int2 c = pk[r + 2];
        int2 d = pk[r + 3];
        float v0 = __builtin_nontemporal_load(x + (size_t)a.x * DIM + lane);
        float v1 = __builtin_nontemporal_load(x + (size_t)b.x * DIM + lane);
        float v2 = __builtin_nontemporal_load(x + (size_t)c.x * DIM + lane);
        float v3 = __builtin_nontemporal_load(x + (size_t)d.x * DIM + lane);
        if (a.y != cur) { atomicAdd(&csum[(size_t)cur * DIM + lane], acc); acc = 0.f; cur = a.y; }
        acc += v0;
        if (b.y != cur) { atomicAdd(&csum[(size_t)cur * DIM + lane], acc); acc = 0.f; cur = b.y; }
        acc += v1;
        if (c.y != cur) { atomicAdd(&csum[(size_t)cur * DIM + lane], acc); acc = 0.f; cur = c.y; }
        acc += v2;
        if (d.y != cur) { atomicAdd(&csum[(size_t)cur * DIM + lane], acc); acc = 0.f; cur = d.y; }
        acc += v3;
    }
    atomicAdd(&csum[(size_t)cur * DIM + lane], acc);
}

// ---------- K5: pk-driven finish — centroid row on the fly + out + loss ----------
// Per cluster-run in sorted pk: v[d] = (DECAY*avg[d][k] + (1-DECAY)*csum[k][d])/cs[k]
// stored (nontemporal, coalesced 256B/row) to every row of the run; loss
// cross/quad term added ONCE at the run's global start (pk[r-1].y != k).
// Empty clusters contribute 0 to loss (csum=0), correctly skipped.
__global__ __launch_bounds__(256) void k_finish(
    const int2* __restrict__ pk, const float* __restrict__ csum,
    const float* __restrict__ cs, const int* __restrict__ cnt,
    const float* __restrict__ avg, float* __restrict__ out,
    float* __restrict__ loss) {
    const int wgid = blockIdx.x * 4 + (threadIdx.x >> 6);  // 0..4095
    const int lane = threadIdx.x & 63;                     // = dim d
    const int r0   = wgid * 32;

    int prevy = (r0 == 0) ? -1 : pk[r0 - 1].y;
    int cur = -1;
    float v = 0.f;
    for (int r = r0; r < r0 + 32; ++r) {
        int2 a = pk[r];                                    // wave-uniform
        if (a.y != cur) {                                  // wave-uniform branch
            cur = a.y;
            float cv = csum[(size_t)cur * DIM + lane];
            float nv = DECAY * avg[(size_t)lane * KCENT + cur] + (1.0f - DECAY) * cv;
            v = nv / cs[cur];
            if (a.y != prevy) {                            // global run start
                float p = v * fmaf((float)cnt[cur], v, -2.0f * cv);
#pragma unroll
                for (int m = 1; m < 64; m <<= 1) p += __shfl_xor(p, m, 64);
                if (lane == 0) atomicAdd(loss, p * INV_ND);
            }
        }
        prevy = a.y;
        __builtin_nontemporal_store(v, out + (size_t)a.x * DIM + lane);
    }
}

extern "C" void kernel_launch(void* const* d_in, const int* in_sizes, int n_in,
                              void* d_out, int out_size, void* d_ws, size_t ws_size,
                              hipStream_t stream) {
    const float* x            = (const float*)d_in[0];
    const float* cent         = (const float*)d_in[1];
    const float* cluster_size = (const float*)d_in[2];
    const float* avg          = (const float*)d_in[3];
    float* out = (float*)d_out;

    float* ws       = (float*)d_ws;
    float* csum     = ws;                     // K*D
    int*   cnt      = (int*)(ws + 65536);     // K
    float* cs       = ws + 66560;             // K
    int*   ind      = (int*)(ws + 133120);    // N
    int2*  pk       = (int2*)(ws + 264192);   // N int2
    float* xsqp     = ws + 526336;            // 512
    int*   cursor16 = (int*)(ws + 527360);    // 16K
    u32*   centB    = (u32*)(ws + 543744);    // K*68
    float* loss     = out + (size_t)NROWS * DIM;

    k_ctrans <<<32, 256, 0, stream>>>(cent, centB, csum, cursor16);
    k_assign <<<NROWS / 256, 512, 0, stream>>>(x, centB, ind, cnt, xsqp);
    k_scatter<<<NROWS / 256, 256, 0, stream>>>(cluster_size, cnt, ind, xsqp,
                                               cursor16, pk, cs, loss);
    k_segsum <<<NROWS / 128, 256, 0, stream>>>(x, pk, csum);
    k_finish <<<NROWS / 128, 256, 0, stream>>>(pk, csum, cs, cnt, avg, out, loss);
}

// Round 12
// 176.902 us; speedup vs baseline: 1.0423x; 1.0423x over previous
//
#include <hip/hip_runtime.h>
#include <math.h>

#define NROWS 131072
#define DIM   64
#define KCENT 1024
#define DECAY 0.99f
#define EPS_  1e-5f
#define INV_ND (1.0f / ((float)NROWS * (float)DIM))

typedef unsigned int u32;
typedef unsigned short u16;
typedef __attribute__((ext_vector_type(8))) short short8b;
typedef __attribute__((ext_vector_type(16))) float floatx16;
typedef __attribute__((ext_vector_type(4))) float floatx4;   // clang vector: valid
                                                             // for nontemporal builtins

// ---------------- ws layout (float elements) ----------------
// csum    [K*D]    @ 0        (zeroed by k_ctrans)
// cnt     [K]      @ 65536    (int, zeroed by k_ctrans)
// cs      [K]      @ 66560    (written by k_scatter block 0)
// cnewT   [K*D]    @ 67584
// ind     [N]      @ 133120   (int)
// pk      [N]      @ 264192   (int2: {row, cluster} in sorted order)
// xsqp    [512]    @ 526336   (float; per-block sum(x^2) partials)
// cursor16[K*16]   @ 527360   (int, 64B-spread atomic cursors; zeroed by k_ctrans)
// centB   [K*68]   @ 543744   (u32: bf16 hi 32dw | lo 32dw | csq@64 | pad; 272B rows)
//
// loss: mean((x-q)^2) = [Sum x^2 - 2 Sum<cnewT,csum> + Sum cnt*||cnewT||^2]/(N*D)
// v11b (R11 fixed: __builtin_nontemporal_store needs a clang ext_vector, not
// HIP float4 — use floatx4 reinterpret):
//   = R8 (best measured, 178.4us) + two mechanism-sound tweaks:
//   * k_segsum: nontemporal x loads (read-once 33.5MB; protect csum in L2)
//   * k_out: nontemporal out stores (write-once 33.5MB; protect cnewT in L2)

__device__ inline u16 bf16rne(float f) {
    u32 u = __float_as_uint(f);
    return (u16)((u + 0x7FFFu + ((u >> 16) & 1u)) >> 16);
}

// ---------- K1: centroid transpose/split + zero csum/cnt/cursor16 ----------
__global__ void k_ctrans(const float* __restrict__ cent, u32* __restrict__ centB,
                         float* __restrict__ zero_base, int* __restrict__ cursor16) {
    const int t = threadIdx.x, b = blockIdx.x;
    const int gid = b * 256 + t;                 // 0..8191
    float4 z = make_float4(0.f, 0.f, 0.f, 0.f);
    for (int i = gid; i < 16640; i += 8192) ((float4*)zero_base)[i] = z;   // csum+cnt
    if (gid < 4096) ((int4*)cursor16)[gid] = make_int4(0, 0, 0, 0);

    const int k   = b * 32 + (t & 31);
    const int grp = t >> 5;                      // 0..7
    u32* row = centB + (size_t)k * 68;
    float csq = 0.f;
#pragma unroll
    for (int j = 0; j < 4; ++j) {
        int w = grp * 4 + j;                     // dim-pair: dims 2w, 2w+1
        float f0 = cent[(2 * w) * KCENT + k];
        float f1 = cent[(2 * w + 1) * KCENT + k];
        u16 h0 = bf16rne(f0), h1 = bf16rne(f1);
        u16 s0 = bf16rne(f0 - __uint_as_float((u32)h0 << 16));
        u16 s1 = bf16rne(f1 - __uint_as_float((u32)h1 << 16));
        csq = fmaf(f0, f0, fmaf(f1, f1, csq));
        row[w]      = (u32)h0 | ((u32)h1 << 16);
        row[32 + w] = (u32)s0 | ((u32)s1 << 16);
    }
    __shared__ float csq_p[256];
    csq_p[t] = csq;
    __syncthreads();
    if (t < 32) {
        float s = 0.f;
#pragma unroll
        for (int g = 0; g < 8; ++g) s += csq_p[g * 32 + t];
        centB[(size_t)(b * 32 + t) * 68 + 64] = __float_as_uint(s);
    }
}

// ---------- K2: MFMA assignment (R1 structure, best measured) ----------
__global__ __launch_bounds__(512, 4) void k_assign(
    const float* __restrict__ x, const u32* __restrict__ centB,
    int* __restrict__ ind, int* __restrict__ cnt, float* __restrict__ xsqp) {
    __shared__ __align__(16) char buf[2][17408];
    __shared__ int hist[KCENT];
    __shared__ float xsq_lds;
    const int tid  = threadIdx.x;
    const int lane = tid & 63;
    const int wid  = tid >> 6;
    const int half = lane >> 5;
    const int nl   = lane & 31;

    hist[tid] = 0;
    hist[tid + 512] = 0;
    if (tid == 0) xsq_lds = 0.f;

    const int rowbase = blockIdx.x * 256 + wid * 32;

    short8b ah[4], al[4];
    float xsq = 0.f;
    {
        const float* xr = x + (size_t)(rowbase + nl) * DIM;
#pragma unroll
        for (int t4 = 0; t4 < 4; ++t4) {
            int d0 = t4 * 16 + half * 8;
            float4 f0 = *(const float4*)(xr + d0);
            float4 f1 = *(const float4*)(xr + d0 + 4);
            float fv[8] = {f0.x, f0.y, f0.z, f0.w, f1.x, f1.y, f1.z, f1.w};
            short8b va, vb;
#pragma unroll
            for (int j = 0; j < 8; ++j) {
                xsq = fmaf(fv[j], fv[j], xsq);
                u16 h = bf16rne(fv[j]);
                float lo = fv[j] - __uint_as_float((u32)h << 16);
                va[j] = (short)h;
                vb[j] = (short)bf16rne(lo);
            }
            ah[t4] = va;
            al[t4] = vb;
        }
    }
#pragma unroll
    for (int m = 1; m < 64; m <<= 1) xsq += __shfl_xor(xsq, m, 64);

    float best[16];
#pragma unroll
    for (int r = 0; r < 16; ++r) best[r] = __uint_as_float(0xFF800000u);

    const char* gbase = (const char*)centB;
#define STAGE(KT, DST)                                                              \
    {                                                                               \
        const char* _src = gbase + (size_t)(KT) * 17408;                            \
        for (int b = wid; b < 17; b += 8) {                                         \
            __builtin_amdgcn_global_load_lds(                                       \
                (const __attribute__((address_space(1))) u32*)(_src + b * 1024 +    \
                                                               lane * 16),          \
                (__attribute__((address_space(3))) u32*)((DST) + b * 1024),         \
                16, 0, 0);                                                          \
        }                                                                           \
    }

    STAGE(0, buf[0]);
    __syncthreads();
    if (lane == 0) atomicAdd(&xsq_lds, xsq);

    for (int kt = 0; kt < 16; ++kt) {
        char* b = buf[kt & 1];
        if (kt < 15) STAGE(kt + 1, buf[(kt + 1) & 1]);

#pragma unroll
        for (int sub = 0; sub < 2; ++sub) {
            const char* base = b + (size_t)(sub * 32 + nl) * 272 + half * 16;
            short8b bh[4], bl[4];
#pragma unroll
            for (int t4 = 0; t4 < 4; ++t4) bh[t4] = *(const short8b*)(base + t4 * 32);
#pragma unroll
            for (int t4 = 0; t4 < 4; ++t4) bl[t4] = *(const short8b*)(base + 128 + t4 * 32);
            float cq = *(const float*)(b + (size_t)(sub * 32 + nl) * 272 + 256);
            float mh = -0.5f * cq;

            floatx16 acc;
#pragma unroll
            for (int i = 0; i < 16; ++i) acc[i] = mh;
#pragma unroll
            for (int t4 = 0; t4 < 4; ++t4)
                acc = __builtin_amdgcn_mfma_f32_32x32x16_bf16(ah[t4], bh[t4], acc, 0, 0, 0);
#pragma unroll
            for (int t4 = 0; t4 < 4; ++t4)
                acc = __builtin_amdgcn_mfma_f32_32x32x16_bf16(ah[t4], bl[t4], acc, 0, 0, 0);
#pragma unroll
            for (int t4 = 0; t4 < 4; ++t4)
                acc = __builtin_amdgcn_mfma_f32_32x32x16_bf16(al[t4], bh[t4], acc, 0, 0, 0);

            const u32 tag = (u32)(kt * 2 + sub);
#pragma unroll
            for (int r = 0; r < 16; ++r) {
                u32 pkv = (__float_as_uint(acc[r]) & 0xFFFFFFE0u) | tag;
                best[r] = fmaxf(best[r], __uint_as_float(pkv));
            }
        }
        __syncthreads();
    }
#undef STAGE

#pragma unroll
    for (int r = 0; r < 16; ++r) {
        float b0 = best[r];
        int   i0 = ((int)(__float_as_uint(b0) & 31u) << 5) | nl;
#pragma unroll
        for (int m = 1; m < 32; m <<= 1) {
            float bp = __shfl_xor(b0, m, 64);
            int   ip = __shfl_xor(i0, m, 64);
            if (bp > b0 || (bp == b0 && ip < i0)) { b0 = bp; i0 = ip; }
        }
        if (nl == 0) {
            int mrow = (r & 3) + 8 * (r >> 2) + 4 * half;
            ind[rowbase + mrow] = i0;
            atomicAdd(&hist[i0], 1);
        }
    }
    __syncthreads();
    {
        int v0 = hist[tid];
        if (v0) atomicAdd(&cnt[tid], v0);
        int v1 = hist[tid + 512];
        if (v1) atomicAdd(&cnt[tid + 512], v1);
    }
    if (tid == 0) xsqp[blockIdx.x] = xsq_lds;
}

// ---------- K3: scatter + fused per-block redundant scan ----------
__global__ __launch_bounds__(256) void k_scatter(
    const float* __restrict__ cluster_size, const int* __restrict__ cnt,
    const int* __restrict__ ind, const float* __restrict__ xsqp,
    int* __restrict__ cursor16, int2* __restrict__ pk,
    float* __restrict__ cs, float* __restrict__ loss) {
    __shared__ int   lh[KCENT];
    __shared__ int   start_l[KCENT];
    __shared__ int   wtot[4];
    __shared__ float wsum[4];
    __shared__ float red4[4];
    const int t = threadIdx.x, b = blockIdx.x;
    const int lane = t & 63, w = t >> 6;

    // Phase A: scan inputs + wave-level partials + lh zero
    const int4   cv = ((const int4*)cnt)[t];             // k = 4t..4t+3
    const float4 cz = ((const float4*)cluster_size)[t];
    float cls0 = DECAY * cz.x + (1.0f - DECAY) * (float)cv.x;
    float cls1 = DECAY * cz.y + (1.0f - DECAY) * (float)cv.y;
    float cls2 = DECAY * cz.z + (1.0f - DECAY) * (float)cv.z;
    float cls3 = DECAY * cz.w + (1.0f - DECAY) * (float)cv.w;

    int s1 = cv.x, s2 = s1 + cv.y, s3 = s2 + cv.z, s4 = s3 + cv.w;
    int inc = s4;
#pragma unroll
    for (int m = 1; m < 64; m <<= 1) {
        int u = __shfl_up(inc, m, 64);
        if (lane >= m) inc += u;
    }
    float fsum = cls0 + cls1 + cls2 + cls3;
#pragma unroll
    for (int m = 1; m < 64; m <<= 1) fsum += __shfl_xor(fsum, m, 64);
    if (lane == 63) wtot[w] = inc;
    if (lane == 0)  wsum[w] = fsum;
    lh[4 * t + 0] = 0; lh[4 * t + 1] = 0; lh[4 * t + 2] = 0; lh[4 * t + 3] = 0;
    if (b == 0 && t < 128) {
        float v = xsqp[t] + xsqp[t + 128] + xsqp[t + 256] + xsqp[t + 384];
#pragma unroll
        for (int m = 1; m < 64; m <<= 1) v += __shfl_xor(v, m, 64);
        if (lane == 0) red4[w] = v;
    }
    __syncthreads();

    // Phase B: start_l; block 0 emits cs + loss x^2 term; ranks via LDS atomics
    int woffv = 0;
#pragma unroll
    for (int i = 0; i < 4; ++i) if (i < w) woffv += wtot[i];
    const int base0 = woffv + inc - s4;
    start_l[4 * t + 0] = base0;
    start_l[4 * t + 1] = base0 + s1;
    start_l[4 * t + 2] = base0 + s2;
    start_l[4 * t + 3] = base0 + s3;
    if (b == 0) {
        const float ntot = wsum[0] + wsum[1] + wsum[2] + wsum[3];
        const float csc = ntot / (ntot + KCENT * EPS_);
        ((float4*)cs)[t] = make_float4((cls0 + EPS_) * csc, (cls1 + EPS_) * csc,
                                       (cls2 + EPS_) * csc, (cls3 + EPS_) * csc);
        if (t == 0) loss[0] = (red4[0] + red4[1]) * INV_ND;
    }
    const int n  = b * 256 + t;
    const int bi = ind[n];
    const int rank = atomicAdd(&lh[bi], 1);
    __syncthreads();

    // Phase C: one global cursor claim per distinct cluster in block
#pragma unroll
    for (int i = 0; i < 4; ++i) {
        int k = t + i * 256;
        int c = lh[k];
        int bse = 0;
        if (c) bse = atomicAdd(&cursor16[k * 16], c);
        lh[k] = start_l[k] + bse;
    }
    __syncthreads();

    pk[lh[bi] + rank] = make_int2(n, bi);
}

// ---------- K4: segment sum, 4-row ILP, nontemporal x (read-once stream) ----------
__global__ __launch_bounds__(256) void k_segsum(
    const float* __restrict__ x, const int2* __restrict__ pk,
    float* __restrict__ csum) {
    const int wgid = blockIdx.x * 4 + (threadIdx.x >> 6);  // 0..4095
    const int lane = threadIdx.x & 63;
    const int r0   = wgid * 32;

    float acc = 0.f;
    int cur = pk[r0].y;
    for (int r = r0; r < r0 + 32; r += 4) {
        int2 a = pk[r];                   // wave-uniform scalar loads
        int2 b = pk[r + 1];
        int2 c = pk[r + 2];
        int2 d = pk[r + 3];
        float v0 = __builtin_nontemporal_load(x + (size_t)a.x * DIM + lane);
        float v1 = __builtin_nontemporal_load(x + (size_t)b.x * DIM + lane);
        float v2 = __builtin_nontemporal_load(x + (size_t)c.x * DIM + lane);
        float v3 = __builtin_nontemporal_load(x + (size_t)d.x * DIM + lane);
        if (a.y != cur) { atomicAdd(&csum[(size_t)cur * DIM + lane], acc); acc = 0.f; cur = a.y; }
        acc += v0;
        if (b.y != cur) { atomicAdd(&csum[(size_t)cur * DIM + lane], acc); acc = 0.f; cur = b.y; }
        acc += v1;
        if (c.y != cur) { atomicAdd(&csum[(size_t)cur * DIM + lane], acc); acc = 0.f; cur = c.y; }
        acc += v2;
        if (d.y != cur) { atomicAdd(&csum[(size_t)cur * DIM + lane], acc); acc = 0.f; cur = d.y; }
        acc += v3;
    }
    atomicAdd(&csum[(size_t)cur * DIM + lane], acc);
}

// ---------- K5: centroids_new [K][D] + loss cross/quad terms ----------
__global__ __launch_bounds__(256) void k_newcent(
    const float* __restrict__ avg, const float* __restrict__ csum,
    const float* __restrict__ cs, const int* __restrict__ cnt,
    float* __restrict__ cnewT, float* __restrict__ loss) {
    int idx = blockIdx.x * 256 + threadIdx.x;         // = k*64 + d
    int k = idx >> 6, d = idx & 63;
    float cv = csum[idx];
    float v = DECAY * avg[d * KCENT + k] + (1.0f - DECAY) * cv;
    v = v / cs[k];
    cnewT[idx] = v;
    float p = v * (fmaf((float)cnt[k], v, -2.0f * cv));

    __shared__ float red[256];
    red[threadIdx.x] = p;
    __syncthreads();
    for (int off = 128; off > 0; off >>= 1) {
        if (threadIdx.x < off) red[threadIdx.x] += red[threadIdx.x + off];
        __syncthreads();
    }
    if (threadIdx.x == 0) atomicAdd(loss, red[0] * INV_ND);
}

// ---------- K6: gather-store, sequential coalesced out, nontemporal stores ----------
__global__ __launch_bounds__(256) void k_out(
    const int* __restrict__ ind, const float* __restrict__ cnewT,
    float* __restrict__ out) {
    const int tid = threadIdx.x;
    const int l16 = tid & 15;
#pragma unroll
    for (int it = 0; it < 4; ++it) {
        int g = blockIdx.x + it * 2048;               // 8192 groups of 16 rows
        int row = g * 16 + (tid >> 4);
        int k = ind[row];
        floatx4 q = ((const floatx4*)(cnewT + (size_t)k * DIM))[l16];
        __builtin_nontemporal_store(q, (floatx4*)(out + (size_t)row * DIM) + l16);
    }
}

extern "C" void kernel_launch(void* const* d_in, const int* in_sizes, int n_in,
                              void* d_out, int out_size, void* d_ws, size_t ws_size,
                              hipStream_t stream) {
    const float* x            = (const float*)d_in[0];
    const float* cent         = (const float*)d_in[1];
    const float* cluster_size = (const float*)d_in[2];
    const float* avg          = (const float*)d_in[3];
    float* out = (float*)d_out;

    float* ws       = (float*)d_ws;
    float* csum     = ws;                     // K*D
    int*   cnt      = (int*)(ws + 65536);     // K
    float* cs       = ws + 66560;             // K
    float* cnewT    = ws + 67584;             // K*D
    int*   ind      = (int*)(ws + 133120);    // N
    int2*  pk       = (int2*)(ws + 264192);   // N int2
    float* xsqp     = ws + 526336;            // 512
    int*   cursor16 = (int*)(ws + 527360);    // 16K
    u32*   centB    = (u32*)(ws + 543744);    // K*68
    float* loss     = out + (size_t)NROWS * DIM;

    k_ctrans <<<32, 256, 0, stream>>>(cent, centB, csum, cursor16);
    k_assign <<<NROWS / 256, 512, 0, stream>>>(x, centB, ind, cnt, xsqp);
    k_scatter<<<NROWS / 256, 256, 0, stream>>>(cluster_size, cnt, ind, xsqp,
                                               cursor16, pk, cs, loss);
    k_segsum <<<NROWS / 128, 256, 0, stream>>>(x, pk, csum);
    k_newcent<<<(KCENT * DIM) / 256, 256, 0, stream>>>(avg, csum, cs, cnt, cnewT, loss);
    k_out    <<<2048, 256, 0, stream>>>(ind, cnewT, out);
}